// Round 1
// baseline (337.389 us; speedup 1.0000x reference)
//
#include <hip/hip_runtime.h>
#include <hip/hip_bf16.h>

#define B_N 16384
#define D_N 512
#define M_N 16

typedef __attribute__((ext_vector_type(4))) float  f32x4;
typedef __attribute__((ext_vector_type(8))) short  s16x8;
typedef __attribute__((ext_vector_type(4))) short  s16x4;

__device__ __forceinline__ short bf16_of(float f) {
  union { float f; unsigned u; } v; v.f = f;
  unsigned r = v.u + 0x7fffu + ((v.u >> 16) & 1u);  // round-to-nearest-even
  return (short)(r >> 16);
}

// ---------------------------------------------------------------------------
// Kernel 1: w^T[d,m] = sum_e Psi[m,d,e] * gt[m,e]   (f32, exact-path for gates)
// grid (16, 8) x 256 threads
// ---------------------------------------------------------------------------
__global__ void k_w(const float* __restrict__ Psi, const float* __restrict__ gt,
                    float* __restrict__ wT) {
  int m = blockIdx.x;
  __shared__ float g[D_N];
  for (int i = threadIdx.x; i < D_N; i += 256) g[i] = gt[m * D_N + i];
  __syncthreads();
  int wave = threadIdx.x >> 6, lane = threadIdx.x & 63;
  int d0 = blockIdx.y * 64;
  for (int d = d0 + wave; d < d0 + 64; d += 4) {
    const float* row = Psi + ((size_t)m * D_N + d) * D_N;
    const f32x4* r4 = (const f32x4*)(row + lane * 8);
    const f32x4* g4 = (const f32x4*)(g + lane * 8);
    f32x4 a0 = r4[0], a1 = r4[1];
    f32x4 b0 = g4[0], b1 = g4[1];
    float s = a0[0]*b0[0] + a0[1]*b0[1] + a0[2]*b0[2] + a0[3]*b0[3]
            + a1[0]*b1[0] + a1[1]*b1[1] + a1[2]*b1[2] + a1[3]*b1[3];
    #pragma unroll
    for (int off = 32; off; off >>= 1) s += __shfl_down(s, off);
    if (lane == 0) wT[d * M_N + m] = s;
  }
}

// ---------------------------------------------------------------------------
// Kernel 2: gates[b,m] = relu(2*sigmoid(z[b,:]·wT[:,m]) - 1)   (all f32)
// grid (B/16) x 256 threads; thread t -> row t>>4, m t&15
// ---------------------------------------------------------------------------
__global__ void k_gates(const float* __restrict__ z, const float* __restrict__ wT,
                        float* __restrict__ gates) {
  __shared__ float zs[16][D_N];
  int t = threadIdx.x;
  size_t b0 = (size_t)blockIdx.x * 16;
  for (int i = t; i < 16 * D_N; i += 256) {
    int r = i >> 9, c = i & 511;
    zs[r][c] = z[(b0 + r) * D_N + c];
  }
  __syncthreads();
  int r = t >> 4, m = t & 15;
  float s0 = 0.f, s1 = 0.f, s2 = 0.f, s3 = 0.f;
  #pragma unroll 4
  for (int e = 0; e < D_N; e += 4) {
    s0 += zs[r][e + 0] * wT[(e + 0) * M_N + m];
    s1 += zs[r][e + 1] * wT[(e + 1) * M_N + m];
    s2 += zs[r][e + 2] * wT[(e + 2) * M_N + m];
    s3 += zs[r][e + 3] * wT[(e + 3) * M_N + m];
  }
  float s = (s0 + s1) + (s2 + s3);
  float sig = 1.f / (1.f + expf(-s));
  gates[(b0 + r) * M_N + m] = fmaxf(2.f * sig - 1.f, 0.f);
}

// ---------------------------------------------------------------------------
// Kernel 3: Psib[m][e][d] = bf16(Psi[m][d][e])   (transpose + convert)
// grid (8, 8, 16) x 256 threads, 64x64 tiles via LDS
// ---------------------------------------------------------------------------
__global__ void k_tr(const float* __restrict__ Psi, short* __restrict__ Psib) {
  int m = blockIdx.z;
  int d0 = blockIdx.x << 6, e0 = blockIdx.y << 6;
  __shared__ short tile[64][65];
  int t = threadIdx.x;
  const float* src = Psi + (size_t)m * D_N * D_N;
  #pragma unroll
  for (int j = 0; j < 16; ++j) {
    int idx = t + (j << 8);
    int r = idx >> 6, c = idx & 63;
    tile[r][c] = bf16_of(src[(size_t)(d0 + r) * D_N + e0 + c]);
  }
  __syncthreads();
  short* dst = Psib + (size_t)m * D_N * D_N;
  #pragma unroll
  for (int j = 0; j < 16; ++j) {
    int idx = t + (j << 8);
    int r = idx >> 6, c = idx & 63;
    dst[(size_t)(e0 + r) * D_N + d0 + c] = tile[c][r];
  }
}

// ---------------------------------------------------------------------------
// Kernel 4: dz[b,e] = sum_m gates[b,m] * (z @ Psi_m)[b,e]
// One GEMM: M=16384, N=512, K=8192 (m-major). A = gate*z formed during staging.
// 128x128 tile, BK=64, 4 waves (2x2), double-buffered LDS, XOR-swizzled,
// 16x16x32 bf16 MFMA, f32 accumulate.
// grid (4, 128) x 256 threads
// ---------------------------------------------------------------------------
__global__ __launch_bounds__(256, 2) void k_gemm(
    const float* __restrict__ z, const float* __restrict__ gates,
    const short* __restrict__ Psib, float* __restrict__ dz) {
  __shared__ short Abuf[2][128 * 64];
  __shared__ short Bbuf[2][128 * 64];
  const int tid = threadIdx.x;
  const int brow = blockIdx.y, bcol = blockIdx.x;
  const int lane = tid & 63;
  const int wid = tid >> 6;
  const int wr = wid >> 1, wc = wid & 1;

  f32x4 acc[4][4] = {};

  f32x4 areg[8];
  float greg[8];
  s16x8 breg[4];

  auto load_tile = [&](int kt) {
    int m  = kt >> 3;
    int kk = (kt & 7) << 6;
    #pragma unroll
    for (int j = 0; j < 8; ++j) {
      int c = tid + (j << 8);
      int row = c >> 4, col4 = c & 15;
      size_t grow = (size_t)brow * 128 + row;
      areg[j] = *(const f32x4*)(z + grow * D_N + kk + col4 * 4);
      greg[j] = gates[grow * M_N + m];
    }
    #pragma unroll
    for (int j = 0; j < 4; ++j) {
      int c = tid + (j << 8);
      int row = c >> 3, col8 = c & 7;
      breg[j] = *(const s16x8*)(Psib + ((size_t)m * D_N + bcol * 128 + row) * D_N
                                + kk + col8 * 8);
    }
  };

  auto write_tile = [&](int buf) {
    #pragma unroll
    for (int j = 0; j < 8; ++j) {
      int c = tid + (j << 8);
      int row = c >> 4, col4 = c & 15;
      int byteoff = ((row << 7) + (col4 << 3)) ^ ((row & 7) << 4);
      s16x4 y;
      #pragma unroll
      for (int k = 0; k < 4; ++k) y[k] = bf16_of(areg[j][k] * greg[j]);
      *(s16x4*)((char*)&Abuf[buf][0] + byteoff) = y;
    }
    #pragma unroll
    for (int j = 0; j < 4; ++j) {
      int c = tid + (j << 8);
      int row = c >> 3, col8 = c & 7;
      int byteoff = ((row << 7) + (col8 << 4)) ^ ((row & 7) << 4);
      *(s16x8*)((char*)&Bbuf[buf][0] + byteoff) = breg[j];
    }
  };

  auto compute = [&](int buf) {
    #pragma unroll
    for (int ks = 0; ks < 2; ++ks) {
      s16x8 a[4], b[4];
      #pragma unroll
      for (int mf = 0; mf < 4; ++mf) {
        int row = wr * 64 + mf * 16 + (lane & 15);
        int byteoff = ((row << 7) + (ks << 6) + ((lane >> 4) << 4)) ^ ((row & 7) << 4);
        a[mf] = *(const s16x8*)((const char*)&Abuf[buf][0] + byteoff);
      }
      #pragma unroll
      for (int nf = 0; nf < 4; ++nf) {
        int row = wc * 64 + nf * 16 + (lane & 15);
        int byteoff = ((row << 7) + (ks << 6) + ((lane >> 4) << 4)) ^ ((row & 7) << 4);
        b[nf] = *(const s16x8*)((const char*)&Bbuf[buf][0] + byteoff);
      }
      #pragma unroll
      for (int mf = 0; mf < 4; ++mf)
        #pragma unroll
        for (int nf = 0; nf < 4; ++nf)
          acc[mf][nf] = __builtin_amdgcn_mfma_f32_16x16x32_bf16(
              a[mf], b[nf], acc[mf][nf], 0, 0, 0);
    }
  };

  load_tile(0);
  write_tile(0);
  __syncthreads();

  for (int kt = 0; kt < 128; ++kt) {
    int cur = kt & 1;
    if (kt < 127) load_tile(kt + 1);   // issue global loads early (hide under MFMA)
    compute(cur);
    if (kt < 127) write_tile(cur ^ 1); // land LDS writes late
    __syncthreads();
  }

  #pragma unroll
  for (int mf = 0; mf < 4; ++mf) {
    #pragma unroll
    for (int nf = 0; nf < 4; ++nf) {
      int col = bcol * 128 + wc * 64 + nf * 16 + (lane & 15);
      size_t rbase = (size_t)brow * 128 + wr * 64 + mf * 16 + ((lane >> 4) << 2);
      #pragma unroll
      for (int j = 0; j < 4; ++j) {
        dz[(rbase + j) * D_N + col] = acc[mf][nf][j];
      }
    }
  }
}

// ---------------------------------------------------------------------------
extern "C" void kernel_launch(void* const* d_in, const int* in_sizes, int n_in,
                              void* d_out, int out_size, void* d_ws, size_t ws_size,
                              hipStream_t stream) {
  // inputs: d_in[0]=t (unused), d_in[1]=z [B,D], d_in[2]=Psi [M,D,D], d_in[3]=gt [M,D]
  const float* z   = (const float*)d_in[1];
  const float* Psi = (const float*)d_in[2];
  const float* gt  = (const float*)d_in[3];
  float* dz = (float*)d_out;

  // ws layout: wT (512*16 f32) | gates (16384*16 f32) | Psib (16*512*512 bf16)
  // total = 32KB + 1MB + 8MB = ~9.03 MB
  float* wT    = (float*)d_ws;
  float* gates = wT + (size_t)D_N * M_N;
  short* Psib  = (short*)(gates + (size_t)B_N * M_N);

  k_w    <<<dim3(M_N, 8),      dim3(256), 0, stream>>>(Psi, gt, wT);
  k_gates<<<dim3(B_N / 16),    dim3(256), 0, stream>>>(z, wT, gates);
  k_tr   <<<dim3(8, 8, M_N),   dim3(256), 0, stream>>>(Psi, Psib);
  k_gemm <<<dim3(4, B_N / 128), dim3(256), 0, stream>>>(z, gates, Psib, dz);
}

// Round 2
// 208.724 us; speedup vs baseline: 1.6164x; 1.6164x over previous
//
#include <hip/hip_runtime.h>
#include <hip/hip_bf16.h>

#define B_N 16384
#define D_N 512
#define M_N 16

typedef __attribute__((ext_vector_type(4))) float  f32x4;
typedef __attribute__((ext_vector_type(8))) short  s16x8;

__device__ __forceinline__ short bf16_of(float f) {
  union { float f; unsigned u; } v; v.f = f;
  unsigned r = v.u + 0x7fffu + ((v.u >> 16) & 1u);  // round-to-nearest-even
  return (short)(r >> 16);
}

// async global->LDS, 16B per lane; LDS dest = wave-uniform base + lane*16
__device__ __forceinline__ void gload_lds16(const void* g, void* l) {
  __builtin_amdgcn_global_load_lds(
      (const __attribute__((address_space(1))) unsigned*)g,
      (__attribute__((address_space(3))) unsigned*)l, 16, 0, 0);
}

// ---------------------------------------------------------------------------
// Kernel 1: w^T[d,m] = sum_e Psi[m,d,e] * gt[m,e]   (f32, exact-path for gates)
// ---------------------------------------------------------------------------
__global__ void k_w(const float* __restrict__ Psi, const float* __restrict__ gt,
                    float* __restrict__ wT) {
  int m = blockIdx.x;
  __shared__ float g[D_N];
  for (int i = threadIdx.x; i < D_N; i += 256) g[i] = gt[m * D_N + i];
  __syncthreads();
  int wave = threadIdx.x >> 6, lane = threadIdx.x & 63;
  int d0 = blockIdx.y * 64;
  for (int d = d0 + wave; d < d0 + 64; d += 4) {
    const float* row = Psi + ((size_t)m * D_N + d) * D_N;
    const f32x4* r4 = (const f32x4*)(row + lane * 8);
    const f32x4* g4 = (const f32x4*)(g + lane * 8);
    f32x4 a0 = r4[0], a1 = r4[1];
    f32x4 b0 = g4[0], b1 = g4[1];
    float s = a0[0]*b0[0] + a0[1]*b0[1] + a0[2]*b0[2] + a0[3]*b0[3]
            + a1[0]*b1[0] + a1[1]*b1[1] + a1[2]*b1[2] + a1[3]*b1[3];
    #pragma unroll
    for (int off = 32; off; off >>= 1) s += __shfl_down(s, off);
    if (lane == 0) wT[d * M_N + m] = s;
  }
}

// ---------------------------------------------------------------------------
// Kernel 2: gates[b,m] = relu(2*sigmoid(z[b,:]·wT[:,m]) - 1)   (all f32)
// ---------------------------------------------------------------------------
__global__ void k_gates(const float* __restrict__ z, const float* __restrict__ wT,
                        float* __restrict__ gates) {
  __shared__ float zs[16][D_N];
  int t = threadIdx.x;
  size_t b0 = (size_t)blockIdx.x * 16;
  for (int i = t; i < 16 * D_N; i += 256) {
    int r = i >> 9, c = i & 511;
    zs[r][c] = z[(b0 + r) * D_N + c];
  }
  __syncthreads();
  int r = t >> 4, m = t & 15;
  float s0 = 0.f, s1 = 0.f, s2 = 0.f, s3 = 0.f;
  #pragma unroll 4
  for (int e = 0; e < D_N; e += 4) {
    s0 += zs[r][e + 0] * wT[(e + 0) * M_N + m];
    s1 += zs[r][e + 1] * wT[(e + 1) * M_N + m];
    s2 += zs[r][e + 2] * wT[(e + 2) * M_N + m];
    s3 += zs[r][e + 3] * wT[(e + 3) * M_N + m];
  }
  float s = (s0 + s1) + (s2 + s3);
  float sig = 1.f / (1.f + expf(-s));
  gates[(b0 + r) * M_N + m] = fmaxf(2.f * sig - 1.f, 0.f);
}

// ---------------------------------------------------------------------------
// Kernel 3: zb[r][.] = bf16(z[r][.]) with 16B-blocks XOR-swizzled by (r&7)
// within each 128B chunk, so that linear global_load_lds lands the GEMM's
// swizzled LDS layout. ws[p] = data[p ^ ((r&7)<<4)] (byte offsets).
// ---------------------------------------------------------------------------
__global__ void k_zb(const float* __restrict__ z, short* __restrict__ zb) {
  int gid = blockIdx.x * 256 + threadIdx.x;   // one 16B output block each
  int r = gid >> 6;                           // row
  int blk = gid & 63;                         // 16B block within 1024B row
  int chunk = blk >> 3;                       // which 128B chunk (64-col group)
  int ib = blk & 7;                           // block within chunk
  int sb = ib ^ (r & 7);                      // source block (XOR involution)
  const float* s = z + (size_t)r * D_N + chunk * 64 + sb * 8;
  f32x4 a = *(const f32x4*)s;
  f32x4 b = *(const f32x4*)(s + 4);
  s16x8 o;
  #pragma unroll
  for (int k = 0; k < 4; ++k) { o[k] = bf16_of(a[k]); o[4 + k] = bf16_of(b[k]); }
  *(s16x8*)(zb + (size_t)r * D_N + blk * 8) = o;
}

// ---------------------------------------------------------------------------
// Kernel 4: Psib[m][e][d] = bf16(Psi[m][d][e]), same per-row (e&7) pre-swizzle
// ---------------------------------------------------------------------------
__global__ void k_tr(const float* __restrict__ Psi, short* __restrict__ Psib) {
  int m = blockIdx.z;
  int d0 = blockIdx.x << 6, e0 = blockIdx.y << 6;
  __shared__ short tile[64][65];
  int t = threadIdx.x;
  const float* src = Psi + (size_t)m * D_N * D_N;
  #pragma unroll
  for (int j = 0; j < 16; ++j) {
    int idx = t + (j << 8);
    int r = idx >> 6, c = idx & 63;
    tile[r][c] = bf16_of(src[(size_t)(d0 + r) * D_N + e0 + c]);
  }
  __syncthreads();
  short* dst = Psib + (size_t)m * D_N * D_N;
  #pragma unroll
  for (int it = 0; it < 2; ++it) {
    int idx = t + (it << 8);          // 512 16B-blocks in the 64(e) x 64(d) tile
    int el = idx >> 3, jb = idx & 7;  // e-local row, logical 8-short block
    int e = e0 + el;
    s16x8 o;
    #pragma unroll
    for (int k = 0; k < 8; ++k) o[k] = tile[jb * 8 + k][el];
    int db = jb ^ (e & 7);            // swizzled destination block
    *(s16x8*)(dst + (size_t)e * D_N + d0 + db * 8) = o;
  }
}

// ---------------------------------------------------------------------------
// Kernel 5: dz[b,e] = sum_m gates[b,m] * (z @ Psi_m)[b,e]
// Single GEMM M=16384,N=512,K=8192 (m-major K). 128x128 tile, BK=64, 4 waves,
// double-buffered LDS via global_load_lds (pre-swizzled sources), gates folded
// into the accumulator at each m-chunk boundary (every 8 K-steps).
// ---------------------------------------------------------------------------
__global__ __launch_bounds__(256, 2) void k_gemm(
    const short* __restrict__ zb16, const float* __restrict__ gates,
    const short* __restrict__ Psib, float* __restrict__ dz) {
  __shared__ short Abuf[2][128 * 64];
  __shared__ short Bbuf[2][128 * 64];
  const int tid = threadIdx.x;
  const int brow = blockIdx.y, bcol = blockIdx.x;
  const int lane = tid & 63;
  const int wid = tid >> 6;
  const int wr = wid >> 1, wc = wid & 1;

  const char* zb = (const char*)zb16;
  const char* pb = (const char*)Psib;
  const int rsub = lane >> 3;          // row within 8-row/1KB chunk
  const int cb = (lane & 7) << 4;      // byte within 128B row

  f32x4 acc[4][4] = {};
  f32x4 accm[4][4] = {};

  auto stage = [&](int buf, int kt) {
    int m = kt >> 3;
    int kkb = (kt & 7) << 7;           // K-chunk byte offset within 1024B row
    #pragma unroll
    for (int j = 0; j < 4; ++j) {
      int rloc = ((wid * 4 + j) << 3) + rsub;
      const char* ga = zb + (((size_t)(brow * 128 + rloc)) << 10) + kkb + cb;
      gload_lds16(ga, (char*)&Abuf[buf][0] + ((wid * 4 + j) << 10));
      const char* gb = pb + (((size_t)(m * D_N + bcol * 128 + rloc)) << 10) + kkb + cb;
      gload_lds16(gb, (char*)&Bbuf[buf][0] + ((wid * 4 + j) << 10));
    }
  };

  auto compute = [&](int buf) {
    #pragma unroll
    for (int ks = 0; ks < 2; ++ks) {
      s16x8 a[4], b[4];
      #pragma unroll
      for (int mf = 0; mf < 4; ++mf) {
        int row = wr * 64 + mf * 16 + (lane & 15);
        int byteoff = ((row << 7) + (ks << 6) + ((lane >> 4) << 4)) ^ ((row & 7) << 4);
        a[mf] = *(const s16x8*)((const char*)&Abuf[buf][0] + byteoff);
      }
      #pragma unroll
      for (int nf = 0; nf < 4; ++nf) {
        int row = wc * 64 + nf * 16 + (lane & 15);
        int byteoff = ((row << 7) + (ks << 6) + ((lane >> 4) << 4)) ^ ((row & 7) << 4);
        b[nf] = *(const s16x8*)((const char*)&Bbuf[buf][0] + byteoff);
      }
      #pragma unroll
      for (int mf = 0; mf < 4; ++mf)
        #pragma unroll
        for (int nf = 0; nf < 4; ++nf)
          accm[mf][nf] = __builtin_amdgcn_mfma_f32_16x16x32_bf16(
              a[mf], b[nf], accm[mf][nf], 0, 0, 0);
    }
  };

  auto apply_gates = [&](int m) {
    #pragma unroll
    for (int mf = 0; mf < 4; ++mf) {
      size_t rbase = (size_t)brow * 128 + wr * 64 + mf * 16 + ((lane >> 4) << 2);
      #pragma unroll
      for (int j = 0; j < 4; ++j) {
        float g = gates[(rbase + j) * M_N + m];
        #pragma unroll
        for (int nf = 0; nf < 4; ++nf)
          acc[mf][nf][j] += g * accm[mf][nf][j];
      }
    }
    #pragma unroll
    for (int mf = 0; mf < 4; ++mf)
      #pragma unroll
      for (int nf = 0; nf < 4; ++nf)
        accm[mf][nf] = f32x4{0.f, 0.f, 0.f, 0.f};
  };

  stage(0, 0);
  __syncthreads();

  for (int kt = 0; kt < 128; ++kt) {
    int cur = kt & 1;
    if (kt < 127) stage(cur ^ 1, kt + 1);  // async gl_lds, hidden under MFMA
    compute(cur);
    if ((kt & 7) == 7) apply_gates(kt >> 3);
    __syncthreads();                        // drains vmcnt+lgkm, flips buffer
  }

  #pragma unroll
  for (int mf = 0; mf < 4; ++mf) {
    #pragma unroll
    for (int nf = 0; nf < 4; ++nf) {
      int col = bcol * 128 + wc * 64 + nf * 16 + (lane & 15);
      size_t rbase = (size_t)brow * 128 + wr * 64 + mf * 16 + ((lane >> 4) << 2);
      #pragma unroll
      for (int j = 0; j < 4; ++j) {
        dz[(rbase + j) * D_N + col] = acc[mf][nf][j];
      }
    }
  }
}

// ---------------------------------------------------------------------------
extern "C" void kernel_launch(void* const* d_in, const int* in_sizes, int n_in,
                              void* d_out, int out_size, void* d_ws, size_t ws_size,
                              hipStream_t stream) {
  const float* z   = (const float*)d_in[1];
  const float* Psi = (const float*)d_in[2];
  const float* gt  = (const float*)d_in[3];
  float* dz = (float*)d_out;

  // ws: wT 32KB | gates 1MB | Psib 8MB | zb16 16MB  (~25MB total)
  float* wT    = (float*)d_ws;
  float* gates = wT + (size_t)D_N * M_N;
  short* Psib  = (short*)(gates + (size_t)B_N * M_N);
  short* zb16  = Psib + (size_t)M_N * D_N * D_N;

  k_w    <<<dim3(M_N, 8),          dim3(256), 0, stream>>>(Psi, gt, wT);
  k_gates<<<dim3(B_N / 16),        dim3(256), 0, stream>>>(z, wT, gates);
  k_zb   <<<dim3(B_N * 64 / 256),  dim3(256), 0, stream>>>(z, zb16);
  k_tr   <<<dim3(8, 8, M_N),       dim3(256), 0, stream>>>(Psi, Psib);
  k_gemm <<<dim3(4, B_N / 128),    dim3(256), 0, stream>>>(zb16, gates, Psib, dz);
}

// Round 3
// 208.227 us; speedup vs baseline: 1.6203x; 1.0024x over previous
//
#include <hip/hip_runtime.h>
#include <hip/hip_bf16.h>

#define B_N 16384
#define D_N 512
#define M_N 16
#define NT  128          // K-tiles: 16 m * 8 chunks of 64

typedef __attribute__((ext_vector_type(4))) float  f32x4;
typedef __attribute__((ext_vector_type(8))) short  s16x8;

__device__ __forceinline__ short bf16_of(float f) {
  union { float f; unsigned u; } v; v.f = f;
  unsigned r = v.u + 0x7fffu + ((v.u >> 16) & 1u);  // RNE
  return (short)(r >> 16);
}
__device__ __forceinline__ float f32_of_bf16(unsigned short u) {
  union { unsigned u; float f; } v; v.u = ((unsigned)u) << 16; return v.f;
}
__device__ __forceinline__ void gload_lds16(const void* g, void* l) {
  __builtin_amdgcn_global_load_lds(
      (const __attribute__((address_space(1))) unsigned*)g,
      (__attribute__((address_space(3))) unsigned*)l, 16, 0, 0);
}

// ---------------------------------------------------------------------------
// Kernel 1 (fused): Psib[m][e][d] = bf16(Psi[m][d][e]) pre-swizzled, AND
// wT[d,m] = sum_e Psi[m,d,e]*gt[m,e] (f32, no atomics: block owns (d-tile,m)).
// grid (8 d-tiles, 16 m) x 256
// ---------------------------------------------------------------------------
__global__ void k_trw(const float* __restrict__ Psi, const float* __restrict__ gt,
                      short* __restrict__ Psib, float* __restrict__ wT) {
  int m = blockIdx.y, d0 = blockIdx.x << 6;
  __shared__ float tile[64][65];
  __shared__ float gs[D_N];
  int t = threadIdx.x;
  for (int i = t; i < D_N; i += 256) gs[i] = gt[m * D_N + i];
  int r = t >> 2, q = t & 3;
  float wacc = 0.f;
  const float* src = Psi + (size_t)m * D_N * D_N;
  short* dst = Psib + (size_t)m * D_N * D_N;
  for (int e0 = 0; e0 < D_N; e0 += 64) {
    __syncthreads();   // protect tile from previous iteration's readers
    #pragma unroll
    for (int j = 0; j < 4; ++j) {
      int idx = t + (j << 8);           // f32x4 unit among 1024
      int rr = idx >> 4, c4 = idx & 15;
      *(f32x4*)&tile[rr][c4 * 4] = *(const f32x4*)(src + (size_t)(d0 + rr) * D_N + e0 + c4 * 4);
    }
    __syncthreads();
    #pragma unroll
    for (int k = 0; k < 16; ++k) wacc += tile[r][q * 16 + k] * gs[e0 + q * 16 + k];
    #pragma unroll
    for (int it = 0; it < 2; ++it) {
      int idx = t + (it << 8);          // 16B-block among 512 (64 e-rows x 8)
      int el = idx >> 3, jb = idx & 7;
      int e = e0 + el;
      s16x8 o;
      #pragma unroll
      for (int k = 0; k < 8; ++k) o[k] = bf16_of(tile[jb * 8 + k][el]);
      int db = jb ^ (e & 7);            // pre-swizzle (involution)
      *(s16x8*)(dst + (size_t)e * D_N + d0 + db * 8) = o;
    }
  }
  wacc += __shfl_xor(wacc, 1);
  wacc += __shfl_xor(wacc, 2);
  if (q == 0) wT[(d0 + r) * M_N + m] = wacc;
}

// ---------------------------------------------------------------------------
// Kernel 2 (fused): gates (bf16) + pre-swizzled bf16 z, one z read.
// grid B/16 x 256
// ---------------------------------------------------------------------------
__global__ void k_gz(const float* __restrict__ z, const float* __restrict__ wT,
                     short* __restrict__ zb, unsigned short* __restrict__ gatesb) {
  __shared__ float zs[16][D_N];
  int t = threadIdx.x;
  size_t b0 = (size_t)blockIdx.x * 16;
  #pragma unroll
  for (int j = 0; j < 8; ++j) {
    int idx = t + (j << 8);             // f32x4 unit among 2048
    int r = idx >> 7, c4 = idx & 127;
    *(f32x4*)&zs[r][c4 * 4] = *(const f32x4*)(z + (b0 + r) * D_N + c4 * 4);
  }
  __syncthreads();
  int r = t >> 4, m = t & 15;
  float s0 = 0.f, s1 = 0.f, s2 = 0.f, s3 = 0.f;
  #pragma unroll 4
  for (int e = 0; e < D_N; e += 4) {
    s0 += zs[r][e + 0] * wT[(e + 0) * M_N + m];
    s1 += zs[r][e + 1] * wT[(e + 1) * M_N + m];
    s2 += zs[r][e + 2] * wT[(e + 2) * M_N + m];
    s3 += zs[r][e + 3] * wT[(e + 3) * M_N + m];
  }
  float s = (s0 + s1) + (s2 + s3);
  float sig = 1.f / (1.f + expf(-s));
  gatesb[(b0 + r) * M_N + m] = (unsigned short)bf16_of(fmaxf(2.f * sig - 1.f, 0.f));
  #pragma unroll
  for (int j = 0; j < 4; ++j) {
    int idx = t + (j << 8);             // 16B block among 1024 (16 rows x 64)
    int rr = idx >> 6, blk = idx & 63;
    int chunk = blk >> 3, ib = blk & 7;
    int sb = ib ^ (rr & 7);             // b0 % 16 == 0, so (b0+rr)&7 == rr&7
    const float* sp = &zs[rr][chunk * 64 + sb * 8];
    s16x8 o;
    #pragma unroll
    for (int k = 0; k < 8; ++k) o[k] = bf16_of(sp[k]);
    *(s16x8*)(zb + (b0 + rr) * D_N + blk * 8) = o;
  }
}

// ---------------------------------------------------------------------------
// Kernel 3: GEMM dz = sum_m g_m * (z @ Psi_m).  256x128 tile, BK=64, 8 waves,
// NBUF=3 LDS rotation, 4-phase interleave, counted vmcnt(6) (never 0 in
// steady state), setprio around MFMA, XCD-chunked block mapping.
// grid 256 x 512
// ---------------------------------------------------------------------------
__global__ __launch_bounds__(512, 2) void k_gemm(
    const char* __restrict__ zb, const unsigned short* __restrict__ gatesb,
    const char* __restrict__ pb, float* __restrict__ dz) {
  // 3 bufs x (A 32KB + B 16KB) + gates 8KB = 152KB
  __shared__ __align__(16) char smem[3 * 49152 + 8192];
  char* gates_lds = smem + 3 * 49152;

  const int tid = threadIdx.x;
  const int lane = tid & 63;
  const int wid = tid >> 6;            // 0..7
  const int wr = wid >> 1, wc = wid & 1;
  const int bid = blockIdx.x;
  const int xcd = bid & 7;             // dispatch round-robins XCDs
  const int bcol = xcd >> 1;           // each XCD owns one B-panel (2MB, L2-fit)
  const int brow = ((xcd & 1) << 5) + (bid >> 3);

  // stage gates (bf16) to LDS: 256 rows x 16 m = 4096 ushort = 8KB
  {
    s16x8 gv = *(const s16x8*)(gatesb + ((size_t)brow << 12) + (tid << 3));
    *(s16x8*)(gates_lds + (tid << 4)) = gv;
  }

  const int rsub = lane >> 3, cbyte = (lane & 7) << 4;
  size_t srcA[4]; int dstA[4];
  #pragma unroll
  for (int j = 0; j < 4; ++j) {
    int c = wid + (j << 3);            // A chunk: 8 rows each, 32 chunks
    srcA[j] = ((size_t)(brow * 256 + c * 8 + rsub) << 10) + cbyte;
    dstA[j] = c << 10;
  }
  size_t srcB[2]; int dstB[2];
  #pragma unroll
  for (int j = 0; j < 2; ++j) {
    int c = wid + (j << 3);            // B chunk: 16 chunks
    srcB[j] = ((size_t)(bcol * 128 + c * 8 + rsub) << 10) + cbyte;
    dstB[j] = 32768 + (c << 10);
  }
  int offA[4][2], offB[4][2];
  #pragma unroll
  for (int f = 0; f < 4; ++f) {
    #pragma unroll
    for (int ks = 0; ks < 2; ++ks) {
      int rowA = wr * 64 + f * 16 + (lane & 15);
      offA[f][ks] = ((rowA << 7) + (ks << 6) + ((lane >> 4) << 4)) ^ ((rowA & 7) << 4);
      int rowB = wc * 64 + f * 16 + (lane & 15);
      offB[f][ks] = 32768 + (((rowB << 7) + (ks << 6) + ((lane >> 4) << 4)) ^ ((rowB & 7) << 4));
    }
  }

  f32x4 acc[4][4] = {};
  f32x4 accm[4][4] = {};

  char* p0 = smem;                 // read this iter
  char* p1 = smem + 49152;         // read next iter
  char* p2 = smem + 2 * 49152;     // stage target (t+2)

  auto stageA = [&](char* buf, int t, int j) {
    gload_lds16(zb + srcA[j] + ((t & 7) << 7), buf + dstA[j]);
  };
  auto stageB = [&](char* buf, int t, int j) {
    gload_lds16(pb + (((size_t)(t >> 3)) << 19) + srcB[j] + ((t & 7) << 7), buf + dstB[j]);
  };

  // prologue: stage tiles 0 and 1 (6 loads each)
  #pragma unroll
  for (int j = 0; j < 4; ++j) stageA(p0, 0, j);
  stageB(p0, 0, 0); stageB(p0, 0, 1);
  #pragma unroll
  for (int j = 0; j < 4; ++j) stageA(p1, 1, j);
  stageB(p1, 1, 0); stageB(p1, 1, 1);
  asm volatile("s_waitcnt vmcnt(6) lgkmcnt(0)" ::: "memory");  // tile0 + gates ready
  __builtin_amdgcn_s_barrier();

  for (int t = 0; t < NT; ++t) {
    const bool st = (t + 2) < NT;
    #pragma unroll
    for (int p = 0; p < 4; ++p) {
      const int mh = p >> 1, nh = p & 1;
      s16x8 av[2][2], bv[2][2];
      #pragma unroll
      for (int i2 = 0; i2 < 2; ++i2) {
        #pragma unroll
        for (int ks = 0; ks < 2; ++ks) {
          av[i2][ks] = *(const s16x8*)(p0 + offA[2 * mh + i2][ks]);
          bv[i2][ks] = *(const s16x8*)(p0 + offB[2 * nh + i2][ks]);
        }
      }
      if (st) {
        if (p == 0)      { stageA(p2, t + 2, 0); stageA(p2, t + 2, 1); }
        else if (p == 1) { stageA(p2, t + 2, 2); stageA(p2, t + 2, 3); }
        else if (p == 2) { stageB(p2, t + 2, 0); }
        else             { stageB(p2, t + 2, 1); }
      }
      __builtin_amdgcn_s_barrier();
      __builtin_amdgcn_s_setprio(1);
      #pragma unroll
      for (int i2 = 0; i2 < 2; ++i2)
        #pragma unroll
        for (int j2 = 0; j2 < 2; ++j2)
          #pragma unroll
          for (int ks = 0; ks < 2; ++ks)
            accm[2 * mh + i2][2 * nh + j2] = __builtin_amdgcn_mfma_f32_16x16x32_bf16(
                av[i2][ks], bv[j2][ks], accm[2 * mh + i2][2 * nh + j2], 0, 0, 0);
      __builtin_amdgcn_s_setprio(0);
      if (p < 3) __builtin_amdgcn_s_barrier();
    }
    if ((t & 7) == 7) {                 // m-chunk boundary: fold gate into acc
      int m = t >> 3;
      #pragma unroll
      for (int mf = 0; mf < 4; ++mf) {
        int rl = wr * 64 + mf * 16 + ((lane >> 4) << 2);
        #pragma unroll
        for (int j = 0; j < 4; ++j) {
          unsigned short gu = *(const unsigned short*)(gates_lds + ((rl + j) << 5) + (m << 1));
          float g = f32_of_bf16(gu);
          #pragma unroll
          for (int nf = 0; nf < 4; ++nf)
            acc[mf][nf][j] += g * accm[mf][nf][j];
        }
      }
      #pragma unroll
      for (int mf = 0; mf < 4; ++mf)
        #pragma unroll
        for (int nf = 0; nf < 4; ++nf)
          accm[mf][nf] = f32x4{0.f, 0.f, 0.f, 0.f};
    }
    if (st) asm volatile("s_waitcnt vmcnt(6)" ::: "memory");   // t+1 landed; t+2 in flight
    else    asm volatile("s_waitcnt vmcnt(0)" ::: "memory");   // epilogue drain
    __builtin_amdgcn_s_barrier();
    char* tmp = p0; p0 = p1; p1 = p2; p2 = tmp;
  }

  #pragma unroll
  for (int mf = 0; mf < 4; ++mf) {
    #pragma unroll
    for (int nf = 0; nf < 4; ++nf) {
      int col = bcol * 128 + wc * 64 + nf * 16 + (lane & 15);
      size_t rbase = (size_t)brow * 256 + wr * 64 + mf * 16 + ((lane >> 4) << 2);
      #pragma unroll
      for (int j = 0; j < 4; ++j)
        dz[(rbase + j) * D_N + col] = acc[mf][nf][j];
    }
  }
}

// ---------------------------------------------------------------------------
extern "C" void kernel_launch(void* const* d_in, const int* in_sizes, int n_in,
                              void* d_out, int out_size, void* d_ws, size_t ws_size,
                              hipStream_t stream) {
  const float* z   = (const float*)d_in[1];
  const float* Psi = (const float*)d_in[2];
  const float* gt  = (const float*)d_in[3];
  float* dz = (float*)d_out;

  // ws: wT 32KB | gatesb 512KB | Psib 8MB | zb16 16MB  (~24.5MB)
  float* wT = (float*)d_ws;
  unsigned short* gatesb = (unsigned short*)((char*)d_ws + 32768);
  short* Psib = (short*)((char*)d_ws + 32768 + 524288);
  short* zb16 = Psib + (size_t)M_N * D_N * D_N;

  k_trw <<<dim3(8, M_N), dim3(256), 0, stream>>>(Psi, gt, Psib, wT);
  k_gz  <<<dim3(B_N / 16), dim3(256), 0, stream>>>(z, wT, zb16, gatesb);
  k_gemm<<<dim3(256), dim3(512), 0, stream>>>((const char*)zb16, gatesb,
                                              (const char*)Psib, dz);
}

// Round 4
// 190.382 us; speedup vs baseline: 1.7722x; 1.0937x over previous
//
#include <hip/hip_runtime.h>
#include <hip/hip_bf16.h>

#define B_N 16384
#define D_N 512
#define M_N 16
#define NT  128          // K-tiles: 16 m * 8 chunks of 64

typedef __attribute__((ext_vector_type(4))) float  f32x4;
typedef __attribute__((ext_vector_type(8))) short  s16x8;

__device__ __forceinline__ short bf16_of(float f) {
  union { float f; unsigned u; } v; v.f = f;
  unsigned r = v.u + 0x7fffu + ((v.u >> 16) & 1u);  // RNE
  return (short)(r >> 16);
}
__device__ __forceinline__ float f32_of_bf16(unsigned short u) {
  union { unsigned u; float f; } v; v.u = ((unsigned)u) << 16; return v.f;
}
__device__ __forceinline__ void gload_lds16(const void* g, void* l) {
  __builtin_amdgcn_global_load_lds(
      (const __attribute__((address_space(1))) unsigned*)g,
      (__attribute__((address_space(3))) unsigned*)l, 16, 0, 0);
}

#define MFMA_ACC(d, x, y) d = __builtin_amdgcn_mfma_f32_16x16x32_bf16(x, y, d, 0, 0, 0)

// ---------------------------------------------------------------------------
// Kernel 1 (fused): Psib[m][e][d] = bf16(Psi[m][d][e]) pre-swizzled, AND
// wT[d,m] = sum_e Psi[m,d,e]*gt[m,e] (f32 exact path for gates).
// ---------------------------------------------------------------------------
__global__ void k_trw(const float* __restrict__ Psi, const float* __restrict__ gt,
                      short* __restrict__ Psib, float* __restrict__ wT) {
  int m = blockIdx.y, d0 = blockIdx.x << 6;
  __shared__ float tile[64][65];
  __shared__ float gs[D_N];
  int t = threadIdx.x;
  for (int i = t; i < D_N; i += 256) gs[i] = gt[m * D_N + i];
  int r = t >> 2, q = t & 3;
  float wacc = 0.f;
  const float* src = Psi + (size_t)m * D_N * D_N;
  short* dst = Psib + (size_t)m * D_N * D_N;
  for (int e0 = 0; e0 < D_N; e0 += 64) {
    __syncthreads();
    #pragma unroll
    for (int j = 0; j < 4; ++j) {
      int idx = t + (j << 8);
      int rr = idx >> 4, c4 = idx & 15;
      *(f32x4*)&tile[rr][c4 * 4] = *(const f32x4*)(src + (size_t)(d0 + rr) * D_N + e0 + c4 * 4);
    }
    __syncthreads();
    #pragma unroll
    for (int k = 0; k < 16; ++k) wacc += tile[r][q * 16 + k] * gs[e0 + q * 16 + k];
    #pragma unroll
    for (int it = 0; it < 2; ++it) {
      int idx = t + (it << 8);
      int el = idx >> 3, jb = idx & 7;
      int e = e0 + el;
      s16x8 o;
      #pragma unroll
      for (int k = 0; k < 8; ++k) o[k] = bf16_of(tile[jb * 8 + k][el]);
      int db = jb ^ (e & 7);
      *(s16x8*)(dst + (size_t)e * D_N + d0 + db * 8) = o;
    }
  }
  wacc += __shfl_xor(wacc, 1);
  wacc += __shfl_xor(wacc, 2);
  if (q == 0) wT[(d0 + r) * M_N + m] = wacc;
}

// ---------------------------------------------------------------------------
// Kernel 2 (fused): gates (bf16) + pre-swizzled bf16 z, one z read.
// ---------------------------------------------------------------------------
__global__ void k_gz(const float* __restrict__ z, const float* __restrict__ wT,
                     short* __restrict__ zb, unsigned short* __restrict__ gatesb) {
  __shared__ float zs[16][D_N];
  int t = threadIdx.x;
  size_t b0 = (size_t)blockIdx.x * 16;
  #pragma unroll
  for (int j = 0; j < 8; ++j) {
    int idx = t + (j << 8);
    int r = idx >> 7, c4 = idx & 127;
    *(f32x4*)&zs[r][c4 * 4] = *(const f32x4*)(z + (b0 + r) * D_N + c4 * 4);
  }
  __syncthreads();
  int r = t >> 4, m = t & 15;
  float s0 = 0.f, s1 = 0.f, s2 = 0.f, s3 = 0.f;
  #pragma unroll 4
  for (int e = 0; e < D_N; e += 4) {
    s0 += zs[r][e + 0] * wT[(e + 0) * M_N + m];
    s1 += zs[r][e + 1] * wT[(e + 1) * M_N + m];
    s2 += zs[r][e + 2] * wT[(e + 2) * M_N + m];
    s3 += zs[r][e + 3] * wT[(e + 3) * M_N + m];
  }
  float s = (s0 + s1) + (s2 + s3);
  float sig = 1.f / (1.f + expf(-s));
  gatesb[(b0 + r) * M_N + m] = (unsigned short)bf16_of(fmaxf(2.f * sig - 1.f, 0.f));
  #pragma unroll
  for (int j = 0; j < 4; ++j) {
    int idx = t + (j << 8);
    int rr = idx >> 6, blk = idx & 63;
    int chunk = blk >> 3, ib = blk & 7;
    int sb = ib ^ (rr & 7);
    const float* sp = &zs[rr][chunk * 64 + sb * 8];
    s16x8 o;
    #pragma unroll
    for (int k = 0; k < 8; ++k) o[k] = bf16_of(sp[k]);
    *(s16x8*)(zb + (b0 + rr) * D_N + blk * 8) = o;
  }
}

// ---------------------------------------------------------------------------
// Kernel 3: GEMM dz = sum_m g_m * (z @ Psi_m).  256x128 tile, BK=64, 8 waves
// (4M x 2N, wave-tile 64x64). NBUF=3, counted vmcnt(6), raw barriers, setprio.
// Per K-tile: ALL 16 fragments register-cached (each read ONCE), 2 phases of
// 8 + 24 MFMA, 4 barriers. Gates in LDS [m][row] (conflict-free fold).
// ---------------------------------------------------------------------------
__global__ __launch_bounds__(512, 2) void k_gemm(
    const char* __restrict__ zb, const unsigned short* __restrict__ gatesb,
    const char* __restrict__ pb, float* __restrict__ dz) {
  __shared__ __align__(128) char smem[3 * 49152 + 8192];
  char* gates_lds = smem + 3 * 49152;

  const int tid = threadIdx.x;
  const int lane = tid & 63;
  const int wid = tid >> 6;            // 0..7
  const int wr = wid >> 1, wc = wid & 1;
  const int bid = blockIdx.x;
  const int xcd = bid & 7;
  const int bcol = xcd >> 1;           // each XCD pair owns one B-panel
  const int brow = ((xcd & 1) << 5) + (bid >> 3);

  // ---- gate staging: LDS layout [m][256 rows] u16 (bank-conflict-free fold)
  {
    s16x8 gv = *(const s16x8*)(gatesb + ((size_t)brow << 12) + ((size_t)tid << 3));
    unsigned short* gl = (unsigned short*)gates_lds;
    int row = tid >> 1, mbase = (tid & 1) << 3;
    #pragma unroll
    for (int k = 0; k < 8; ++k)
      gl[(mbase + k) * 256 + row] = (unsigned short)gv[k];
  }
  asm volatile("s_waitcnt vmcnt(0)" ::: "memory");  // drain gate loads before counting

  // ---- staging addresses (pre-swizzled global sources, linear LDS dests)
  const int rsub = lane >> 3, cbyte = (lane & 7) << 4;
  const size_t srcA0 = ((size_t)(brow * 256 + wid * 8 + rsub) << 10) + cbyte;
  const size_t srcB0 = ((size_t)(bcol * 128 + wid * 8 + rsub) << 10) + cbyte;
  const int dstA0 = wid << 10;
  const int dstB0 = 32768 + (wid << 10);

  auto stageA = [&](char* buf, int t, int j) {
    gload_lds16(zb + srcA0 + (size_t)(j << 16) + ((t & 7) << 7),
                buf + dstA0 + (j << 13));
  };
  auto stageB = [&](char* buf, int t, int j) {
    gload_lds16(pb + (((size_t)(t >> 3)) << 19) + srcB0 + (size_t)(j << 16) + ((t & 7) << 7),
                buf + dstB0 + (j << 13));
  };

  // ---- fragment base offsets; addr(mf,ks) = (base + mf*2048) ^ (ks<<6)
  const int lrow = lane & 15;
  const int swz = (lrow & 7) << 4;
  const int offA0 = ((wr * 64 + lrow) << 7) + (((lane >> 4) << 4) ^ swz);
  const int offB0 = 32768 + ((wc * 64 + lrow) << 7) + (((lane >> 4) << 4) ^ swz);

  f32x4 acc[4][4] = {};
  f32x4 accm[4][4] = {};

  char* p0 = smem;
  char* p1 = smem + 49152;
  char* p2 = smem + 2 * 49152;

  // ---- prologue: stage tiles 0 and 1
  #pragma unroll
  for (int j = 0; j < 4; ++j) stageA(p0, 0, j);
  stageB(p0, 0, 0); stageB(p0, 0, 1);
  #pragma unroll
  for (int j = 0; j < 4; ++j) stageA(p1, 1, j);
  stageB(p1, 1, 0); stageB(p1, 1, 1);
  asm volatile("s_waitcnt vmcnt(6) lgkmcnt(0)" ::: "memory");
  __builtin_amdgcn_s_barrier();

  for (int t = 0; t < NT; ++t) {
    const bool st = (t + 2) < NT;
    s16x8 a[4][2], b[4][2];

    // ---- phase 0: read half the frags, issue 3 stage loads, 8 MFMA
    #pragma unroll
    for (int mf = 0; mf < 2; ++mf)
      #pragma unroll
      for (int ks = 0; ks < 2; ++ks) {
        a[mf][ks] = *(const s16x8*)(p0 + ((offA0 + mf * 2048) ^ (ks << 6)));
        b[mf][ks] = *(const s16x8*)(p0 + ((offB0 + mf * 2048) ^ (ks << 6)));
      }
    if (st) { stageA(p2, t + 2, 0); stageA(p2, t + 2, 1); stageA(p2, t + 2, 2); }
    __builtin_amdgcn_s_barrier();
    __builtin_amdgcn_s_setprio(1);
    #pragma unroll
    for (int ks = 0; ks < 2; ++ks) {
      MFMA_ACC(accm[0][0], a[0][ks], b[0][ks]);
      MFMA_ACC(accm[0][1], a[0][ks], b[1][ks]);
      MFMA_ACC(accm[1][0], a[1][ks], b[0][ks]);
      MFMA_ACC(accm[1][1], a[1][ks], b[1][ks]);
    }
    __builtin_amdgcn_s_setprio(0);
    __builtin_amdgcn_s_barrier();

    // ---- phase 1: read remaining frags, issue 3 stage loads, 24 MFMA
    #pragma unroll
    for (int mf = 2; mf < 4; ++mf)
      #pragma unroll
      for (int ks = 0; ks < 2; ++ks) {
        a[mf][ks] = *(const s16x8*)(p0 + ((offA0 + mf * 2048) ^ (ks << 6)));
        b[mf][ks] = *(const s16x8*)(p0 + ((offB0 + mf * 2048) ^ (ks << 6)));
      }
    if (st) { stageA(p2, t + 2, 3); stageB(p2, t + 2, 0); stageB(p2, t + 2, 1); }
    __builtin_amdgcn_s_barrier();
    __builtin_amdgcn_s_setprio(1);
    #pragma unroll
    for (int ks = 0; ks < 2; ++ks) {
      MFMA_ACC(accm[0][2], a[0][ks], b[2][ks]);
      MFMA_ACC(accm[0][3], a[0][ks], b[3][ks]);
      MFMA_ACC(accm[1][2], a[1][ks], b[2][ks]);
      MFMA_ACC(accm[1][3], a[1][ks], b[3][ks]);
      MFMA_ACC(accm[2][0], a[2][ks], b[0][ks]);
      MFMA_ACC(accm[2][1], a[2][ks], b[1][ks]);
      MFMA_ACC(accm[3][0], a[3][ks], b[0][ks]);
      MFMA_ACC(accm[3][1], a[3][ks], b[1][ks]);
      MFMA_ACC(accm[2][2], a[2][ks], b[2][ks]);
      MFMA_ACC(accm[2][3], a[2][ks], b[3][ks]);
      MFMA_ACC(accm[3][2], a[3][ks], b[2][ks]);
      MFMA_ACC(accm[3][3], a[3][ks], b[3][ks]);
    }
    __builtin_amdgcn_s_setprio(0);

    if ((t & 7) == 7) {                 // m-chunk boundary: fold gate into acc
      int m = t >> 3;
      const unsigned short* gl = (const unsigned short*)gates_lds;
      #pragma unroll
      for (int mf = 0; mf < 4; ++mf) {
        int rl = wr * 64 + mf * 16 + ((lane >> 4) << 2);
        #pragma unroll
        for (int j = 0; j < 4; ++j) {
          float g = f32_of_bf16(gl[m * 256 + rl + j]);
          #pragma unroll
          for (int nf = 0; nf < 4; ++nf)
            acc[mf][nf][j] += g * accm[mf][nf][j];
        }
      }
      #pragma unroll
      for (int mf = 0; mf < 4; ++mf)
        #pragma unroll
        for (int nf = 0; nf < 4; ++nf)
          accm[mf][nf] = f32x4{0.f, 0.f, 0.f, 0.f};
    }

    if (st) asm volatile("s_waitcnt vmcnt(6)" ::: "memory");  // t+1 landed, t+2 in flight
    else    asm volatile("s_waitcnt vmcnt(0)" ::: "memory");  // epilogue drain
    __builtin_amdgcn_s_barrier();
    char* tmp = p0; p0 = p1; p1 = p2; p2 = tmp;
  }

  #pragma unroll
  for (int mf = 0; mf < 4; ++mf) {
    #pragma unroll
    for (int nf = 0; nf < 4; ++nf) {
      int col = bcol * 128 + wc * 64 + nf * 16 + (lane & 15);
      size_t rbase = (size_t)brow * 256 + wr * 64 + mf * 16 + ((lane >> 4) << 2);
      #pragma unroll
      for (int j = 0; j < 4; ++j)
        dz[(rbase + j) * D_N + col] = acc[mf][nf][j];
    }
  }
}

// ---------------------------------------------------------------------------
extern "C" void kernel_launch(void* const* d_in, const int* in_sizes, int n_in,
                              void* d_out, int out_size, void* d_ws, size_t ws_size,
                              hipStream_t stream) {
  const float* z   = (const float*)d_in[1];
  const float* Psi = (const float*)d_in[2];
  const float* gt  = (const float*)d_in[3];
  float* dz = (float*)d_out;

  // ws: wT 32KB | gatesb 512KB | Psib 8MB | zb16 16MB  (~24.5MB)
  float* wT = (float*)d_ws;
  unsigned short* gatesb = (unsigned short*)((char*)d_ws + 32768);
  short* Psib = (short*)((char*)d_ws + 32768 + 524288);
  short* zb16 = Psib + (size_t)M_N * D_N * D_N;

  k_trw <<<dim3(8, M_N), dim3(256), 0, stream>>>(Psi, gt, Psib, wT);
  k_gz  <<<dim3(B_N / 16), dim3(256), 0, stream>>>(z, wT, zb16, gatesb);
  k_gemm<<<dim3(256), dim3(512), 0, stream>>>((const char*)zb16, gatesb,
                                              (const char*)Psib, dz);
}

// Round 5
// 177.167 us; speedup vs baseline: 1.9044x; 1.0746x over previous
//
#include <hip/hip_runtime.h>
#include <hip/hip_bf16.h>

#define B_N 16384
#define D_N 512
#define M_N 16
#define NT  128          // K-tiles: 16 m * 8 chunks of 64

typedef __attribute__((ext_vector_type(4))) float  f32x4;
typedef __attribute__((ext_vector_type(8))) short  s16x8;

__device__ __forceinline__ short bf16_of(float f) {
  union { float f; unsigned u; } v; v.f = f;
  unsigned r = v.u + 0x7fffu + ((v.u >> 16) & 1u);  // RNE
  return (short)(r >> 16);
}
__device__ __forceinline__ float f32_of_bf16(unsigned short u) {
  union { unsigned u; float f; } v; v.u = ((unsigned)u) << 16; return v.f;
}
__device__ __forceinline__ void gload_lds16(const void* g, void* l) {
  __builtin_amdgcn_global_load_lds(
      (const __attribute__((address_space(1))) unsigned*)g,
      (__attribute__((address_space(3))) unsigned*)l, 16, 0, 0);
}

#define MFMA_ACC(d, x, y) d = __builtin_amdgcn_mfma_f32_16x16x32_bf16(x, y, d, 0, 0, 0)

// ---------------------------------------------------------------------------
// Kernel 1 (fused): Psib[m][e][d] = bf16(Psi[m][d][e]) pre-swizzled, AND
// wT[d,m] = sum_e Psi[m,d,e]*gt[m,e] (f32 exact path for gates).
// ---------------------------------------------------------------------------
__global__ void k_trw(const float* __restrict__ Psi, const float* __restrict__ gt,
                      short* __restrict__ Psib, float* __restrict__ wT) {
  int m = blockIdx.y, d0 = blockIdx.x << 6;
  __shared__ float tile[64][65];
  __shared__ float gs[D_N];
  int t = threadIdx.x;
  for (int i = t; i < D_N; i += 256) gs[i] = gt[m * D_N + i];
  int r = t >> 2, q = t & 3;
  float wacc = 0.f;
  const float* src = Psi + (size_t)m * D_N * D_N;
  short* dst = Psib + (size_t)m * D_N * D_N;
  for (int e0 = 0; e0 < D_N; e0 += 64) {
    __syncthreads();
    #pragma unroll
    for (int j = 0; j < 4; ++j) {
      int idx = t + (j << 8);
      int rr = idx >> 4, c4 = idx & 15;
      *(f32x4*)&tile[rr][c4 * 4] = *(const f32x4*)(src + (size_t)(d0 + rr) * D_N + e0 + c4 * 4);
    }
    __syncthreads();
    #pragma unroll
    for (int k = 0; k < 16; ++k) wacc += tile[r][q * 16 + k] * gs[e0 + q * 16 + k];
    #pragma unroll
    for (int it = 0; it < 2; ++it) {
      int idx = t + (it << 8);
      int el = idx >> 3, jb = idx & 7;
      int e = e0 + el;
      s16x8 o;
      #pragma unroll
      for (int k = 0; k < 8; ++k) o[k] = bf16_of(tile[jb * 8 + k][el]);
      int db = jb ^ (e & 7);
      *(s16x8*)(dst + (size_t)e * D_N + d0 + db * 8) = o;
    }
  }
  wacc += __shfl_xor(wacc, 1);
  wacc += __shfl_xor(wacc, 2);
  if (q == 0) wT[(d0 + r) * M_N + m] = wacc;
}

// ---------------------------------------------------------------------------
// Kernel 2 (fused): gates (bf16) + pre-swizzled bf16 z, one z read.
// ---------------------------------------------------------------------------
__global__ void k_gz(const float* __restrict__ z, const float* __restrict__ wT,
                     short* __restrict__ zb, unsigned short* __restrict__ gatesb) {
  __shared__ float zs[16][D_N];
  int t = threadIdx.x;
  size_t b0 = (size_t)blockIdx.x * 16;
  #pragma unroll
  for (int j = 0; j < 8; ++j) {
    int idx = t + (j << 8);
    int r = idx >> 7, c4 = idx & 127;
    *(f32x4*)&zs[r][c4 * 4] = *(const f32x4*)(z + (b0 + r) * D_N + c4 * 4);
  }
  __syncthreads();
  int r = t >> 4, m = t & 15;
  float s0 = 0.f, s1 = 0.f, s2 = 0.f, s3 = 0.f;
  #pragma unroll 4
  for (int e = 0; e < D_N; e += 4) {
    s0 += zs[r][e + 0] * wT[(e + 0) * M_N + m];
    s1 += zs[r][e + 1] * wT[(e + 1) * M_N + m];
    s2 += zs[r][e + 2] * wT[(e + 2) * M_N + m];
    s3 += zs[r][e + 3] * wT[(e + 3) * M_N + m];
  }
  float s = (s0 + s1) + (s2 + s3);
  float sig = 1.f / (1.f + expf(-s));
  gatesb[(b0 + r) * M_N + m] = (unsigned short)bf16_of(fmaxf(2.f * sig - 1.f, 0.f));
  #pragma unroll
  for (int j = 0; j < 4; ++j) {
    int idx = t + (j << 8);
    int rr = idx >> 6, blk = idx & 63;
    int chunk = blk >> 3, ib = blk & 7;
    int sb = ib ^ (rr & 7);
    const float* sp = &zs[rr][chunk * 64 + sb * 8];
    s16x8 o;
    #pragma unroll
    for (int k = 0; k < 8; ++k) o[k] = bf16_of(sp[k]);
    *(s16x8*)(zb + (b0 + rr) * D_N + blk * 8) = o;
  }
}

// ---------------------------------------------------------------------------
// Kernel 3: GEMM dz = sum_m g_m * (z @ Psi_m).  256x128 tile, BK=64, 8 waves
// (4M x 2N, wave-tile 64x64). NBUF=3, counted vmcnt(6), setprio, 16/16 phases.
// A-CENTRIC XCD map: all 4 bcol-blocks of a brow on one XCD -> the 8 z-slabs
// (2 MB) stay L2-resident across all 16 m-passes; B streams with 8-way share.
// ---------------------------------------------------------------------------
__global__ __launch_bounds__(512, 2) void k_gemm(
    const char* __restrict__ zb, const unsigned short* __restrict__ gatesb,
    const char* __restrict__ pb, float* __restrict__ dz) {
  __shared__ __align__(128) char smem[3 * 49152 + 8192];
  char* gates_lds = smem + 3 * 49152;

  const int tid = threadIdx.x;
  const int lane = tid & 63;
  const int wid = tid >> 6;            // 0..7
  const int wr = wid >> 1, wc = wid & 1;
  const int bid = blockIdx.x;
  const int xcd = bid & 7;
  const int g8  = bid >> 3;            // 0..31 within XCD
  const int bcol = g8 & 3;             // 4 consecutive blocks share a brow
  const int brow = xcd * 8 + (g8 >> 2);// 8 brows per XCD -> A-set 2MB, L2-fit

  // ---- gate staging: LDS layout [m][256 rows] u16 (bank-conflict-free fold)
  {
    s16x8 gv = *(const s16x8*)(gatesb + ((size_t)brow << 12) + ((size_t)tid << 3));
    unsigned short* gl = (unsigned short*)gates_lds;
    int row = tid >> 1, mbase = (tid & 1) << 3;
    #pragma unroll
    for (int k = 0; k < 8; ++k)
      gl[(mbase + k) * 256 + row] = (unsigned short)gv[k];
  }
  asm volatile("s_waitcnt vmcnt(0)" ::: "memory");  // drain gate loads before counting

  // ---- staging addresses (pre-swizzled global sources, linear LDS dests)
  const int rsub = lane >> 3, cbyte = (lane & 7) << 4;
  const size_t srcA0 = ((size_t)(brow * 256 + wid * 8 + rsub) << 10) + cbyte;
  const size_t srcB0 = ((size_t)(bcol * 128 + wid * 8 + rsub) << 10) + cbyte;
  const int dstA0 = wid << 10;
  const int dstB0 = 32768 + (wid << 10);

  auto stageA = [&](char* buf, int t, int j) {
    gload_lds16(zb + srcA0 + (size_t)(j << 16) + ((t & 7) << 7),
                buf + dstA0 + (j << 13));
  };
  auto stageB = [&](char* buf, int t, int j) {
    gload_lds16(pb + (((size_t)(t >> 3)) << 19) + srcB0 + (size_t)(j << 16) + ((t & 7) << 7),
                buf + dstB0 + (j << 13));
  };

  // ---- fragment base offsets; addr(mf,ks) = (base + mf*2048) ^ (ks<<6)
  const int lrow = lane & 15;
  const int swz = (lrow & 7) << 4;
  const int offA0 = ((wr * 64 + lrow) << 7) + (((lane >> 4) << 4) ^ swz);
  const int offB0 = 32768 + ((wc * 64 + lrow) << 7) + (((lane >> 4) << 4) ^ swz);

  f32x4 acc[4][4] = {};
  f32x4 accm[4][4] = {};

  char* p0 = smem;
  char* p1 = smem + 49152;
  char* p2 = smem + 2 * 49152;

  // ---- prologue: stage tiles 0 and 1
  #pragma unroll
  for (int j = 0; j < 4; ++j) stageA(p0, 0, j);
  stageB(p0, 0, 0); stageB(p0, 0, 1);
  #pragma unroll
  for (int j = 0; j < 4; ++j) stageA(p1, 1, j);
  stageB(p1, 1, 0); stageB(p1, 1, 1);
  asm volatile("s_waitcnt vmcnt(6) lgkmcnt(0)" ::: "memory");
  __builtin_amdgcn_s_barrier();

  for (int t = 0; t < NT; ++t) {
    const bool st = (t + 2) < NT;
    s16x8 a[4][2], b[4][2];

    // ---- phase 0: read a[0..1] + all b (12 reads), 3 stage loads, 16 MFMA
    #pragma unroll
    for (int ks = 0; ks < 2; ++ks) {
      a[0][ks] = *(const s16x8*)(p0 + ((offA0 +    0) ^ (ks << 6)));
      a[1][ks] = *(const s16x8*)(p0 + ((offA0 + 2048) ^ (ks << 6)));
      #pragma unroll
      for (int nf = 0; nf < 4; ++nf)
        b[nf][ks] = *(const s16x8*)(p0 + ((offB0 + nf * 2048) ^ (ks << 6)));
    }
    if (st) { stageA(p2, t + 2, 0); stageA(p2, t + 2, 1); stageA(p2, t + 2, 2); }
    __builtin_amdgcn_s_barrier();
    __builtin_amdgcn_s_setprio(1);
    #pragma unroll
    for (int ks = 0; ks < 2; ++ks) {
      MFMA_ACC(accm[0][0], a[0][ks], b[0][ks]);
      MFMA_ACC(accm[0][1], a[0][ks], b[1][ks]);
      MFMA_ACC(accm[1][0], a[1][ks], b[0][ks]);
      MFMA_ACC(accm[1][1], a[1][ks], b[1][ks]);
      MFMA_ACC(accm[0][2], a[0][ks], b[2][ks]);
      MFMA_ACC(accm[0][3], a[0][ks], b[3][ks]);
      MFMA_ACC(accm[1][2], a[1][ks], b[2][ks]);
      MFMA_ACC(accm[1][3], a[1][ks], b[3][ks]);
    }
    __builtin_amdgcn_s_setprio(0);
    __builtin_amdgcn_s_barrier();

    // ---- phase 1: read a[2..3] (4 reads), 3 stage loads, 16 MFMA
    #pragma unroll
    for (int ks = 0; ks < 2; ++ks) {
      a[2][ks] = *(const s16x8*)(p0 + ((offA0 + 2 * 2048) ^ (ks << 6)));
      a[3][ks] = *(const s16x8*)(p0 + ((offA0 + 3 * 2048) ^ (ks << 6)));
    }
    if (st) { stageA(p2, t + 2, 3); stageB(p2, t + 2, 0); stageB(p2, t + 2, 1); }
    __builtin_amdgcn_s_barrier();
    __builtin_amdgcn_s_setprio(1);
    #pragma unroll
    for (int ks = 0; ks < 2; ++ks) {
      MFMA_ACC(accm[2][0], a[2][ks], b[0][ks]);
      MFMA_ACC(accm[2][1], a[2][ks], b[1][ks]);
      MFMA_ACC(accm[3][0], a[3][ks], b[0][ks]);
      MFMA_ACC(accm[3][1], a[3][ks], b[1][ks]);
      MFMA_ACC(accm[2][2], a[2][ks], b[2][ks]);
      MFMA_ACC(accm[2][3], a[2][ks], b[3][ks]);
      MFMA_ACC(accm[3][2], a[3][ks], b[2][ks]);
      MFMA_ACC(accm[3][3], a[3][ks], b[3][ks]);
    }
    __builtin_amdgcn_s_setprio(0);

    if ((t & 7) == 7) {                 // m-chunk boundary: fold gate into acc
      int m = t >> 3;
      const unsigned short* gl = (const unsigned short*)gates_lds;
      #pragma unroll
      for (int mf = 0; mf < 4; ++mf) {
        int rl = wr * 64 + mf * 16 + ((lane >> 4) << 2);
        #pragma unroll
        for (int j = 0; j < 4; ++j) {
          float g = f32_of_bf16(gl[m * 256 + rl + j]);
          #pragma unroll
          for (int nf = 0; nf < 4; ++nf)
            acc[mf][nf][j] += g * accm[mf][nf][j];
        }
      }
      #pragma unroll
      for (int mf = 0; mf < 4; ++mf)
        #pragma unroll
        for (int nf = 0; nf < 4; ++nf)
          accm[mf][nf] = f32x4{0.f, 0.f, 0.f, 0.f};
    }

    if (st) asm volatile("s_waitcnt vmcnt(6)" ::: "memory");  // t+1 landed, t+2 in flight
    else    asm volatile("s_waitcnt vmcnt(0)" ::: "memory");  // epilogue drain
    __builtin_amdgcn_s_barrier();
    char* tmp = p0; p0 = p1; p1 = p2; p2 = tmp;
  }

  #pragma unroll
  for (int mf = 0; mf < 4; ++mf) {
    #pragma unroll
    for (int nf = 0; nf < 4; ++nf) {
      int col = bcol * 128 + wc * 64 + nf * 16 + (lane & 15);
      size_t rbase = (size_t)brow * 256 + wr * 64 + mf * 16 + ((lane >> 4) << 2);
      #pragma unroll
      for (int j = 0; j < 4; ++j)
        dz[(rbase + j) * D_N + col] = acc[mf][nf][j];
    }
  }
}

// ---------------------------------------------------------------------------
extern "C" void kernel_launch(void* const* d_in, const int* in_sizes, int n_in,
                              void* d_out, int out_size, void* d_ws, size_t ws_size,
                              hipStream_t stream) {
  const float* z   = (const float*)d_in[1];
  const float* Psi = (const float*)d_in[2];
  const float* gt  = (const float*)d_in[3];
  float* dz = (float*)d_out;

  // ws: wT 32KB | gatesb 512KB | Psib 8MB | zb16 16MB  (~24.5MB)
  float* wT = (float*)d_ws;
  unsigned short* gatesb = (unsigned short*)((char*)d_ws + 32768);
  short* Psib = (short*)((char*)d_ws + 32768 + 524288);
  short* zb16 = Psib + (size_t)M_N * D_N * D_N;

  k_trw <<<dim3(8, M_N), dim3(256), 0, stream>>>(Psi, gt, Psib, wT);
  k_gz  <<<dim3(B_N / 16), dim3(256), 0, stream>>>(z, wT, zb16, gatesb);
  k_gemm<<<dim3(256), dim3(512), 0, stream>>>((const char*)zb16, gatesb,
                                              (const char*)Psib, dz);
}

// Round 6
// 157.571 us; speedup vs baseline: 2.1412x; 1.1244x over previous
//
#include <hip/hip_runtime.h>
#include <hip/hip_bf16.h>

#define B_N 16384
#define D_N 512
#define M_N 16

typedef __attribute__((ext_vector_type(4))) float  f32x4;
typedef __attribute__((ext_vector_type(8))) short  s16x8;

__device__ __forceinline__ short bf16_of(float f) {
  union { float f; unsigned u; } v; v.f = f;
  unsigned r = v.u + 0x7fffu + ((v.u >> 16) & 1u);  // RNE
  return (short)(r >> 16);
}
__device__ __forceinline__ float f32_of_bf16(unsigned short u) {
  union { unsigned u; float f; } v; v.u = ((unsigned)u) << 16; return v.f;
}
__device__ __forceinline__ void gload_lds16(const void* g, void* l) {
  __builtin_amdgcn_global_load_lds(
      (const __attribute__((address_space(1))) unsigned*)g,
      (__attribute__((address_space(3))) unsigned*)l, 16, 0, 0);
}

#define MFMA_ACC(d, x, y) d = __builtin_amdgcn_mfma_f32_16x16x32_bf16(x, y, d, 0, 0, 0)

// ---------------------------------------------------------------------------
// Kernel 1 (fused): Psib[m][e][d] = bf16(Psi[m][d][e]) pre-swizzled, AND
// wT[d,m] = sum_e Psi[m,d,e]*gt[m,e] (f32 exact path for gates).
// ---------------------------------------------------------------------------
__global__ void k_trw(const float* __restrict__ Psi, const float* __restrict__ gt,
                      short* __restrict__ Psib, float* __restrict__ wT) {
  int m = blockIdx.y, d0 = blockIdx.x << 6;
  __shared__ float tile[64][65];
  __shared__ float gs[D_N];
  int t = threadIdx.x;
  for (int i = t; i < D_N; i += 256) gs[i] = gt[m * D_N + i];
  int r = t >> 2, q = t & 3;
  float wacc = 0.f;
  const float* src = Psi + (size_t)m * D_N * D_N;
  short* dst = Psib + (size_t)m * D_N * D_N;
  for (int e0 = 0; e0 < D_N; e0 += 64) {
    __syncthreads();
    #pragma unroll
    for (int j = 0; j < 4; ++j) {
      int idx = t + (j << 8);
      int rr = idx >> 4, c4 = idx & 15;
      *(f32x4*)&tile[rr][c4 * 4] = *(const f32x4*)(src + (size_t)(d0 + rr) * D_N + e0 + c4 * 4);
    }
    __syncthreads();
    #pragma unroll
    for (int k = 0; k < 16; ++k) wacc += tile[r][q * 16 + k] * gs[e0 + q * 16 + k];
    #pragma unroll
    for (int it = 0; it < 2; ++it) {
      int idx = t + (it << 8);
      int el = idx >> 3, jb = idx & 7;
      int e = e0 + el;
      s16x8 o;
      #pragma unroll
      for (int k = 0; k < 8; ++k) o[k] = bf16_of(tile[jb * 8 + k][el]);
      int db = jb ^ (e & 7);
      *(s16x8*)(dst + (size_t)e * D_N + d0 + db * 8) = o;
    }
  }
  wacc += __shfl_xor(wacc, 1);
  wacc += __shfl_xor(wacc, 2);
  if (q == 0) wT[(d0 + r) * M_N + m] = wacc;
}

// ---------------------------------------------------------------------------
// Kernel 2 (fused): gates (bf16) + pre-swizzled bf16 z, one z read.
// ---------------------------------------------------------------------------
__global__ void k_gz(const float* __restrict__ z, const float* __restrict__ wT,
                     short* __restrict__ zb, unsigned short* __restrict__ gatesb) {
  __shared__ float zs[16][D_N];
  int t = threadIdx.x;
  size_t b0 = (size_t)blockIdx.x * 16;
  #pragma unroll
  for (int j = 0; j < 8; ++j) {
    int idx = t + (j << 8);
    int r = idx >> 7, c4 = idx & 127;
    *(f32x4*)&zs[r][c4 * 4] = *(const f32x4*)(z + (b0 + r) * D_N + c4 * 4);
  }
  __syncthreads();
  int r = t >> 4, m = t & 15;
  float s0 = 0.f, s1 = 0.f, s2 = 0.f, s3 = 0.f;
  #pragma unroll 4
  for (int e = 0; e < D_N; e += 4) {
    s0 += zs[r][e + 0] * wT[(e + 0) * M_N + m];
    s1 += zs[r][e + 1] * wT[(e + 1) * M_N + m];
    s2 += zs[r][e + 2] * wT[(e + 2) * M_N + m];
    s3 += zs[r][e + 3] * wT[(e + 3) * M_N + m];
  }
  float s = (s0 + s1) + (s2 + s3);
  float sig = 1.f / (1.f + expf(-s));
  gatesb[(b0 + r) * M_N + m] = (unsigned short)bf16_of(fmaxf(2.f * sig - 1.f, 0.f));
  #pragma unroll
  for (int j = 0; j < 4; ++j) {
    int idx = t + (j << 8);
    int rr = idx >> 6, blk = idx & 63;
    int chunk = blk >> 3, ib = blk & 7;
    int sb = ib ^ (rr & 7);
    const float* sp = &zs[rr][chunk * 64 + sb * 8];
    s16x8 o;
    #pragma unroll
    for (int k = 0; k < 8; ++k) o[k] = bf16_of(sp[k]);
    *(s16x8*)(zb + (b0 + rr) * D_N + blk * 8) = o;
  }
}

// ---------------------------------------------------------------------------
// Kernel 3: GEMM dz^T-tiles = sum_m g_m * (Psi_m^T @ z^T).  256(b)x128(e)
// block, 8 waves (wr=b-quad 0..3, wc=e-half 0..1), d-OUTER / m-INNER order:
// z-side fragments register-cached per d-chunk (16x fewer A LDS reads);
// Psi-side fragments pipelined in regs (bx/by ping-pong) so ds_read overlaps
// MFMA; ONE barrier per step; NBUF=4 B-buffers, counted vmcnt; swapped MFMA
// operands make the gate constant over acc regs (4 gate reads/step, f32 fold).
// ---------------------------------------------------------------------------
__global__ __launch_bounds__(512, 2) void k_gemm(
    const char* __restrict__ zb, const unsigned short* __restrict__ gatesb,
    const char* __restrict__ pb, float* __restrict__ dz) {
  // A bufs: 2x32KB at 0,32768 | B bufs: 4x16KB at 65536+q*16384 | gates: 131072
  __shared__ __align__(128) char smem[139264];

  const int tid = threadIdx.x;
  const int lane = tid & 63;
  const int wid = tid >> 6;
  const int wr = wid >> 1;             // b-block (64 rows of 256)
  const int wc = wid & 1;              // e-block (64 cols of 128)
  const int bid = blockIdx.x;
  const int xcd = bid & 7;
  const int g8 = bid >> 3;
  const int bcol = g8 & 3;
  const int brow = xcd * 8 + (g8 >> 2);  // A-centric XCD map (L2-resident z)

  // ---- gates -> LDS [m][256 rows] u16
  {
    s16x8 gv = *(const s16x8*)(gatesb + ((size_t)brow << 12) + ((size_t)tid << 3));
    unsigned short* gl = (unsigned short*)(smem + 131072);
    int row = tid >> 1, mbase = (tid & 1) << 3;
    #pragma unroll
    for (int k = 0; k < 8; ++k)
      gl[(mbase + k) * 256 + row] = (unsigned short)gv[k];
  }

  const int rsub = lane >> 3, cbyte = (lane & 7) << 4;

  auto stageA = [&](int ab, int dc) {     // 4 loads: 256 rows x 128B d-chunk
    #pragma unroll
    for (int j = 0; j < 4; ++j) {
      const char* g = zb + (((size_t)(brow * 256 + wid * 8 + j * 64 + rsub)) << 10)
                      + (dc << 7) + cbyte;
      gload_lds16(g, smem + ab * 32768 + (wid << 10) + (j << 13));
    }
  };
  auto stageB = [&](int s) {              // 2 loads: 128 e-rows x 128B d-chunk
    int m = s & 15, dc = s >> 4, q = s & 3;
    #pragma unroll
    for (int j = 0; j < 2; ++j) {
      const char* g = pb + (((size_t)(m * 512 + bcol * 128 + wid * 8 + j * 64 + rsub)) << 10)
                      + (dc << 7) + cbyte;
      gload_lds16(g, smem + 65536 + q * 16384 + (wid << 10) + (j << 13));
    }
  };

  const int lrow = lane & 15;
  const int swz = (lrow & 7) << 4;
  const int kq16 = (((lane >> 4) << 4)) ^ swz;
  const int offY = ((wr * 64 + lrow) << 7) + kq16;   // z frags (y operand)
  const int offX = ((wc * 64 + lrow) << 7) + kq16;   // Psi frags (x operand)

  f32x4 acc[4][4] = {};
  f32x4 accm[4][4] = {};
  s16x8 areg[4][2];
  s16x8 bx[4], by[4];

  // ---- prologue: A(dc0), B(0..2); drain; preload bx <- (s=0, ks0)
  stageA(0, 0);
  stageB(0); stageB(1); stageB(2);
  asm volatile("s_waitcnt vmcnt(0) lgkmcnt(0)" ::: "memory");
  __builtin_amdgcn_s_barrier();
  #pragma unroll
  for (int i = 0; i < 4; ++i)
    bx[i] = *(const s16x8*)(smem + 65536 + (offX + i * 2048));

  for (int s = 0; s < 128; ++s) {
    const int m = s & 15, dc = s >> 4;
    const char* bbase_cur = smem + 65536 + (s & 3) * 16384;
    const char* bbase_nxt = smem + 65536 + ((s + 1) & 3) * 16384;

    // ---- section A: reads (ks1 Psi frags, z frags at dc start), stages, 16 MFMA
    if (m == 0) {
      const char* abase = smem + (dc & 1) * 32768;
      #pragma unroll
      for (int j = 0; j < 4; ++j) {
        areg[j][0] = *(const s16x8*)(abase + (offY + j * 2048));
        areg[j][1] = *(const s16x8*)(abase + ((offY + j * 2048) ^ 64));
      }
    }
    #pragma unroll
    for (int i = 0; i < 4; ++i)
      by[i] = *(const s16x8*)(bbase_cur + ((offX + i * 2048) ^ 64));
    if (s + 3 < 128) stageB(s + 3);
    if (m == 11 && dc < 7) stageA((dc & 1) ^ 1, dc + 1);
    float gj[4];
    {
      const unsigned short* gl = (const unsigned short*)(smem + 131072);
      #pragma unroll
      for (int j = 0; j < 4; ++j)
        gj[j] = f32_of_bf16(gl[m * 256 + wr * 64 + j * 16 + lrow]);
    }
    __builtin_amdgcn_s_setprio(1);
    #pragma unroll
    for (int i = 0; i < 4; ++i)
      #pragma unroll
      for (int j = 0; j < 4; ++j)
        MFMA_ACC(accm[i][j], bx[i], areg[j][0]);
    __builtin_amdgcn_s_setprio(0);

    // ---- section B: read next step's ks0 Psi frags, 16 MFMA, fold, wait
    if (s < 127) {
      #pragma unroll
      for (int i = 0; i < 4; ++i)
        bx[i] = *(const s16x8*)(bbase_nxt + (offX + i * 2048));
    }
    __builtin_amdgcn_s_setprio(1);
    #pragma unroll
    for (int i = 0; i < 4; ++i)
      #pragma unroll
      for (int j = 0; j < 4; ++j)
        MFMA_ACC(accm[i][j], by[i], areg[j][1]);
    __builtin_amdgcn_s_setprio(0);
    #pragma unroll
    for (int i = 0; i < 4; ++i)
      #pragma unroll
      for (int j = 0; j < 4; ++j) {
        #pragma unroll
        for (int jj = 0; jj < 4; ++jj)
          acc[i][j][jj] += gj[j] * accm[i][j][jj];
        accm[i][j] = f32x4{0.f, 0.f, 0.f, 0.f};
      }

    if (dc < 7 && (m == 11 || m == 12))
      asm volatile("s_waitcnt vmcnt(6)" ::: "memory");   // A(dc+1)+2 B-tiles in flight
    else if (s >= 125)
      asm volatile("s_waitcnt vmcnt(0)" ::: "memory");   // epilogue drain
    else
      asm volatile("s_waitcnt vmcnt(2)" ::: "memory");   // B(s+2) landed, B(s+3) in flight
    __builtin_amdgcn_s_barrier();
  }

  // ---- epilogue: acc[i][j][jj] = dzT[e = wc*64+i*16+(lane>>4)*4+jj][b = wr*64+j*16+lrow]
  #pragma unroll
  for (int i = 0; i < 4; ++i) {
    int e = bcol * 128 + wc * 64 + i * 16 + ((lane >> 4) << 2);
    #pragma unroll
    for (int j = 0; j < 4; ++j) {
      size_t b = (size_t)brow * 256 + wr * 64 + j * 16 + lrow;
      *(f32x4*)(dz + b * D_N + e) = acc[i][j];
    }
  }
}

// ---------------------------------------------------------------------------
extern "C" void kernel_launch(void* const* d_in, const int* in_sizes, int n_in,
                              void* d_out, int out_size, void* d_ws, size_t ws_size,
                              hipStream_t stream) {
  const float* z   = (const float*)d_in[1];
  const float* Psi = (const float*)d_in[2];
  const float* gt  = (const float*)d_in[3];
  float* dz = (float*)d_out;

  // ws: wT 32KB | gatesb 512KB | Psib 8MB | zb16 16MB  (~24.5MB)
  float* wT = (float*)d_ws;
  unsigned short* gatesb = (unsigned short*)((char*)d_ws + 32768);
  short* Psib = (short*)((char*)d_ws + 32768 + 524288);
  short* zb16 = Psib + (size_t)M_N * D_N * D_N;

  k_trw <<<dim3(8, M_N), dim3(256), 0, stream>>>(Psi, gt, Psib, wT);
  k_gz  <<<dim3(B_N / 16), dim3(256), 0, stream>>>(z, wT, zb16, gatesb);
  k_gemm<<<dim3(256), dim3(512), 0, stream>>>((const char*)zb16, gatesb,
                                              (const char*)Psib, dz);
}

// Round 7
// 155.148 us; speedup vs baseline: 2.1746x; 1.0156x over previous
//
#include <hip/hip_runtime.h>
#include <hip/hip_bf16.h>

#define B_N 16384
#define D_N 512
#define M_N 16

typedef __attribute__((ext_vector_type(4))) float  f32x4;
typedef __attribute__((ext_vector_type(8))) short  s16x8;

__device__ __forceinline__ short bf16_of(float f) {
  union { float f; unsigned u; } v; v.f = f;
  unsigned r = v.u + 0x7fffu + ((v.u >> 16) & 1u);  // RNE
  return (short)(r >> 16);
}
__device__ __forceinline__ float f32_of_bf16(unsigned short u) {
  union { unsigned u; float f; } v; v.u = ((unsigned)u) << 16; return v.f;
}
__device__ __forceinline__ void gload_lds16(const void* g, void* l) {
  __builtin_amdgcn_global_load_lds(
      (const __attribute__((address_space(1))) unsigned*)g,
      (__attribute__((address_space(3))) unsigned*)l, 16, 0, 0);
}

#define MFMA_ACC(d, x, y) d = __builtin_amdgcn_mfma_f32_16x16x32_bf16(x, y, d, 0, 0, 0)
#define MFMA_Z(d, x, y)   d = __builtin_amdgcn_mfma_f32_16x16x32_bf16(x, y, FZERO, 0, 0, 0)

// ---------------------------------------------------------------------------
// Kernel 1 (fused): Psib[m][e][d] = bf16(Psi[m][d][e]) pre-swizzled, AND
// wT[d,m] = sum_e Psi[m,d,e]*gt[m,e] (f32 exact path for gates).
// ---------------------------------------------------------------------------
__global__ void k_trw(const float* __restrict__ Psi, const float* __restrict__ gt,
                      short* __restrict__ Psib, float* __restrict__ wT) {
  int m = blockIdx.y, d0 = blockIdx.x << 6;
  __shared__ float tile[64][65];
  __shared__ float gs[D_N];
  int t = threadIdx.x;
  for (int i = t; i < D_N; i += 256) gs[i] = gt[m * D_N + i];
  int r = t >> 2, q = t & 3;
  float wacc = 0.f;
  const float* src = Psi + (size_t)m * D_N * D_N;
  short* dst = Psib + (size_t)m * D_N * D_N;
  for (int e0 = 0; e0 < D_N; e0 += 64) {
    __syncthreads();
    #pragma unroll
    for (int j = 0; j < 4; ++j) {
      int idx = t + (j << 8);
      int rr = idx >> 4, c4 = idx & 15;
      *(f32x4*)&tile[rr][c4 * 4] = *(const f32x4*)(src + (size_t)(d0 + rr) * D_N + e0 + c4 * 4);
    }
    __syncthreads();
    #pragma unroll
    for (int k = 0; k < 16; ++k) wacc += tile[r][q * 16 + k] * gs[e0 + q * 16 + k];
    #pragma unroll
    for (int it = 0; it < 2; ++it) {
      int idx = t + (it << 8);
      int el = idx >> 3, jb = idx & 7;
      int e = e0 + el;
      s16x8 o;
      #pragma unroll
      for (int k = 0; k < 8; ++k) o[k] = bf16_of(tile[jb * 8 + k][el]);
      int db = jb ^ (e & 7);
      *(s16x8*)(dst + (size_t)e * D_N + d0 + db * 8) = o;
    }
  }
  wacc += __shfl_xor(wacc, 1);
  wacc += __shfl_xor(wacc, 2);
  if (q == 0) wT[(d0 + r) * M_N + m] = wacc;
}

// ---------------------------------------------------------------------------
// Kernel 2 (fused): gates (bf16) + pre-swizzled bf16 z, one z read.
// ---------------------------------------------------------------------------
__global__ void k_gz(const float* __restrict__ z, const float* __restrict__ wT,
                     short* __restrict__ zb, unsigned short* __restrict__ gatesb) {
  __shared__ float zs[16][D_N];
  int t = threadIdx.x;
  size_t b0 = (size_t)blockIdx.x * 16;
  #pragma unroll
  for (int j = 0; j < 8; ++j) {
    int idx = t + (j << 8);
    int r = idx >> 7, c4 = idx & 127;
    *(f32x4*)&zs[r][c4 * 4] = *(const f32x4*)(z + (b0 + r) * D_N + c4 * 4);
  }
  __syncthreads();
  int r = t >> 4, m = t & 15;
  float s0 = 0.f, s1 = 0.f, s2 = 0.f, s3 = 0.f;
  #pragma unroll 4
  for (int e = 0; e < D_N; e += 4) {
    s0 += zs[r][e + 0] * wT[(e + 0) * M_N + m];
    s1 += zs[r][e + 1] * wT[(e + 1) * M_N + m];
    s2 += zs[r][e + 2] * wT[(e + 2) * M_N + m];
    s3 += zs[r][e + 3] * wT[(e + 3) * M_N + m];
  }
  float s = (s0 + s1) + (s2 + s3);
  float sig = 1.f / (1.f + expf(-s));
  gatesb[(b0 + r) * M_N + m] = (unsigned short)bf16_of(fmaxf(2.f * sig - 1.f, 0.f));
  #pragma unroll
  for (int j = 0; j < 4; ++j) {
    int idx = t + (j << 8);
    int rr = idx >> 6, blk = idx & 63;
    int chunk = blk >> 3, ib = blk & 7;
    int sb = ib ^ (rr & 7);
    const float* sp = &zs[rr][chunk * 64 + sb * 8];
    s16x8 o;
    #pragma unroll
    for (int k = 0; k < 8; ++k) o[k] = bf16_of(sp[k]);
    *(s16x8*)(zb + (b0 + rr) * D_N + blk * 8) = o;
  }
}

// ---------------------------------------------------------------------------
// Kernel 3: GEMM dz^T-tiles = sum_m g_m * (Psi_m^T @ z^T).  256(b)x128(e)
// block, 8 waves, d-OUTER / m-INNER (z frags reg-cached per d-chunk).
// Changes this round: (a) first-MFMA C=0 (no accm zeroing movs), (b) gate
// prefetch one step ahead, (c) gates held as f32 in LDS (no cvt per step).
// ---------------------------------------------------------------------------
__global__ __launch_bounds__(512, 2) void k_gemm(
    const char* __restrict__ zb, const unsigned short* __restrict__ gatesb,
    const char* __restrict__ pb, float* __restrict__ dz) {
  // A bufs: 2x32KB @0 | B bufs: 4x16KB @65536 | gates f32: 16KB @131072
  __shared__ __align__(128) char smem[147456];
  float* glf = (float*)(smem + 131072);

  const int tid = threadIdx.x;
  const int lane = tid & 63;
  const int wid = tid >> 6;
  const int wr = wid >> 1;             // b-block (64 rows of 256)
  const int wc = wid & 1;              // e-block (64 cols of 128)
  const int bid = blockIdx.x;
  const int xcd = bid & 7;
  const int g8 = bid >> 3;
  const int bcol = g8 & 3;
  const int brow = xcd * 8 + (g8 >> 2);  // A-centric XCD map (L2-resident z)

  // ---- gates -> LDS [m][256 rows] f32 (converted once here)
  {
    s16x8 gv = *(const s16x8*)(gatesb + ((size_t)brow << 12) + ((size_t)tid << 3));
    int row = tid >> 1, mbase = (tid & 1) << 3;
    #pragma unroll
    for (int k = 0; k < 8; ++k)
      glf[(mbase + k) * 256 + row] = f32_of_bf16((unsigned short)gv[k]);
  }

  const int rsub = lane >> 3, cbyte = (lane & 7) << 4;

  auto stageA = [&](int ab, int dc) {     // 4 loads: 256 rows x 128B d-chunk
    #pragma unroll
    for (int j = 0; j < 4; ++j) {
      const char* g = zb + (((size_t)(brow * 256 + wid * 8 + j * 64 + rsub)) << 10)
                      + (dc << 7) + cbyte;
      gload_lds16(g, smem + ab * 32768 + (wid << 10) + (j << 13));
    }
  };
  auto stageB = [&](int s) {              // 2 loads: 128 e-rows x 128B d-chunk
    int m = s & 15, dc = s >> 4, q = s & 3;
    #pragma unroll
    for (int j = 0; j < 2; ++j) {
      const char* g = pb + (((size_t)(m * 512 + bcol * 128 + wid * 8 + j * 64 + rsub)) << 10)
                      + (dc << 7) + cbyte;
      gload_lds16(g, smem + 65536 + q * 16384 + (wid << 10) + (j << 13));
    }
  };

  const int lrow = lane & 15;
  const int swz = (lrow & 7) << 4;
  const int kq16 = (((lane >> 4) << 4)) ^ swz;
  const int offY = ((wr * 64 + lrow) << 7) + kq16;   // z frags (y operand)
  const int offX = ((wc * 64 + lrow) << 7) + kq16;   // Psi frags (x operand)
  const int grow = wr * 64 + lrow;                   // gate row base (j*16 offsets)

  f32x4 acc[4][4] = {};
  f32x4 accm[4][4];
  s16x8 areg[4][2];
  s16x8 bx[4], by[4];
  float gjc[4], gjn[4];
  const f32x4 FZERO = {0.f, 0.f, 0.f, 0.f};

  // ---- prologue: A(dc0), B(0..2); drain; preload bx + gates for s=0
  stageA(0, 0);
  stageB(0); stageB(1); stageB(2);
  asm volatile("s_waitcnt vmcnt(0) lgkmcnt(0)" ::: "memory");
  __builtin_amdgcn_s_barrier();
  #pragma unroll
  for (int i = 0; i < 4; ++i)
    bx[i] = *(const s16x8*)(smem + 65536 + (offX + i * 2048));
  #pragma unroll
  for (int j = 0; j < 4; ++j)
    gjc[j] = glf[grow + j * 16];   // m=0

  for (int s = 0; s < 128; ++s) {
    const int m = s & 15, dc = s >> 4;
    const char* bbase_cur = smem + 65536 + (s & 3) * 16384;
    const char* bbase_nxt = smem + 65536 + ((s + 1) & 3) * 16384;

    // ---- reads for this step (z frags at dc start, ks1 Psi frags, next gates)
    if (m == 0) {
      const char* abase = smem + (dc & 1) * 32768;
      #pragma unroll
      for (int j = 0; j < 4; ++j) {
        areg[j][0] = *(const s16x8*)(abase + (offY + j * 2048));
        areg[j][1] = *(const s16x8*)(abase + ((offY + j * 2048) ^ 64));
      }
    }
    #pragma unroll
    for (int i = 0; i < 4; ++i)
      by[i] = *(const s16x8*)(bbase_cur + ((offX + i * 2048) ^ 64));
    {
      const int mn = (s + 1) & 15;
      #pragma unroll
      for (int j = 0; j < 4; ++j)
        gjn[j] = glf[mn * 256 + grow + j * 16];
    }
    if (s + 3 < 128) stageB(s + 3);
    if (m == 11 && dc < 7) stageA((dc & 1) ^ 1, dc + 1);

    // ---- section A: 16 MFMA, C = 0 (kills accm zeroing)
    __builtin_amdgcn_s_setprio(1);
    #pragma unroll
    for (int i = 0; i < 4; ++i)
      #pragma unroll
      for (int j = 0; j < 4; ++j)
        MFMA_Z(accm[i][j], bx[i], areg[j][0]);
    __builtin_amdgcn_s_setprio(0);

    // ---- read next step's ks0 Psi frags (hidden under section-B MFMAs)
    if (s < 127) {
      #pragma unroll
      for (int i = 0; i < 4; ++i)
        bx[i] = *(const s16x8*)(bbase_nxt + (offX + i * 2048));
    }

    // ---- section B: 16 MFMA accumulate, then gated fold (64 fma only)
    __builtin_amdgcn_s_setprio(1);
    #pragma unroll
    for (int i = 0; i < 4; ++i)
      #pragma unroll
      for (int j = 0; j < 4; ++j)
        MFMA_ACC(accm[i][j], by[i], areg[j][1]);
    __builtin_amdgcn_s_setprio(0);
    #pragma unroll
    for (int i = 0; i < 4; ++i)
      #pragma unroll
      for (int j = 0; j < 4; ++j)
        #pragma unroll
        for (int jj = 0; jj < 4; ++jj)
          acc[i][j][jj] = fmaf(gjc[j], accm[i][j][jj], acc[i][j][jj]);
    #pragma unroll
    for (int j = 0; j < 4; ++j) gjc[j] = gjn[j];

    if (dc < 7 && (m == 11 || m == 12))
      asm volatile("s_waitcnt vmcnt(6)" ::: "memory");   // A(dc+1)+2 B-tiles in flight
    else if (s >= 125)
      asm volatile("s_waitcnt vmcnt(0)" ::: "memory");   // epilogue drain
    else
      asm volatile("s_waitcnt vmcnt(2)" ::: "memory");   // B(s+2) landed, B(s+3) in flight
    __builtin_amdgcn_s_barrier();
  }

  // ---- epilogue: acc[i][j][jj] = dzT[e][b]
  #pragma unroll
  for (int i = 0; i < 4; ++i) {
    int e = bcol * 128 + wc * 64 + i * 16 + ((lane >> 4) << 2);
    #pragma unroll
    for (int j = 0; j < 4; ++j) {
      size_t b = (size_t)brow * 256 + wr * 64 + j * 16 + lrow;
      *(f32x4*)(dz + b * D_N + e) = acc[i][j];
    }
  }
}

// ---------------------------------------------------------------------------
extern "C" void kernel_launch(void* const* d_in, const int* in_sizes, int n_in,
                              void* d_out, int out_size, void* d_ws, size_t ws_size,
                              hipStream_t stream) {
  const float* z   = (const float*)d_in[1];
  const float* Psi = (const float*)d_in[2];
  const float* gt  = (const float*)d_in[3];
  float* dz = (float*)d_out;

  // ws: wT 32KB | gatesb 512KB | Psib 8MB | zb16 16MB  (~24.5MB)
  float* wT = (float*)d_ws;
  unsigned short* gatesb = (unsigned short*)((char*)d_ws + 32768);
  short* Psib = (short*)((char*)d_ws + 32768 + 524288);
  short* zb16 = Psib + (size_t)M_N * D_N * D_N;

  k_trw <<<dim3(8, M_N), dim3(256), 0, stream>>>(Psi, gt, Psib, wT);
  k_gz  <<<dim3(B_N / 16), dim3(256), 0, stream>>>(z, wT, zb16, gatesb);
  k_gemm<<<dim3(256), dim3(512), 0, stream>>>((const char*)zb16, gatesb,
                                              (const char*)Psib, dz);
}